// Round 1
// baseline (121.755 us; speedup 1.0000x reference)
//
#include <hip/hip_runtime.h>
#include <math.h>

#define GRID_N 7
#define NB 2
#define NC 20
#define IS 8            // NB*4
#define DCH 30          // NB*5 + NC
#define BATCH 8192
#define NCELL (BATCH * GRID_N * GRID_N)   // 401408
#define INV_GRID (1.0f / 7.0f)
#define INV_BATCH (1.0f / 8192.0f)

__device__ __forceinline__ float bce(float l, float t) {
    // max(l,0) - l*t + log1p(exp(-|l|))
    return fmaxf(l, 0.0f) - l * t + logf(1.0f + expf(-fabsf(l)));
}

__device__ __forceinline__ float box_loss(const float* pb, const float* gb) {
    float dx = pb[0] - gb[0];
    float dy = pb[1] - gb[1];
    float dw = sqrtf(fabsf(pb[2])) - sqrtf(gb[2]);   // ref: sqrt(|pw|), sqrt(gw) no abs
    float dh = sqrtf(fabsf(pb[3])) - sqrtf(gb[3]);
    return dx * dx + dy * dy + dw * dw + dh * dh;
}

__global__ __launch_bounds__(256) void yolo_loss_kernel(
        const float* __restrict__ p, const float* __restrict__ g,
        float* __restrict__ out) {
    const int cell = blockIdx.x * blockDim.x + threadIdx.x;
    float acc = 0.0f;

    if (cell < NCELL) {
        const int ij = cell % (GRID_N * GRID_N);
        const float fi = (float)(ij / GRID_N);   // row
        const float fj = (float)(ij % GRID_N);   // col  (cr = [col, row])

        float pv[DCH], gv[DCH];
        const float2* p2 = reinterpret_cast<const float2*>(p) + (long)cell * (DCH / 2);
        const float2* g2 = reinterpret_cast<const float2*>(g) + (long)cell * (DCH / 2);
        #pragma unroll
        for (int k = 0; k < DCH / 2; ++k) { float2 v = p2[k]; pv[2*k] = v.x; pv[2*k+1] = v.y; }
        #pragma unroll
        for (int k = 0; k < DCH / 2; ++k) { float2 v = g2[k]; gv[2*k] = v.x; gv[2*k+1] = v.y; }

        const float conf_g = gv[IS];

        if (conf_g == 0.0f) {
            // negative cells: 0.5 * sum BCE(conf logits, 0)
            acc = 0.5f * (bce(pv[IS], 0.0f) + bce(pv[IS + 1], 0.0f));
        } else if (conf_g > 0.0f) {
            // ---- class loss ----
            float cls = 0.0f;
            #pragma unroll
            for (int c = 0; c < NC; ++c) cls += bce(pv[NB * 5 + c], gv[NB * 5 + c]);

            // ---- poff = [sigmoid(xy), wh] ----
            float po[NB][4];
            #pragma unroll
            for (int k = 0; k < NB; ++k) {
                po[k][0] = 1.0f / (1.0f + expf(-pv[4*k + 0]));
                po[k][1] = 1.0f / (1.0f + expf(-pv[4*k + 1]));
                po[k][2] = pv[4*k + 2];
                po[k][3] = pv[4*k + 3];
            }

            // ---- ltrb for pred and gt ----
            float pl[NB][4], gl[NB][4], pa[NB], ga[NB];
            #pragma unroll
            for (int k = 0; k < NB; ++k) {
                float cx = (po[k][0] + fj) * INV_GRID;
                float cy = (po[k][1] + fi) * INV_GRID;
                float w = po[k][2], h = po[k][3];
                pl[k][0] = cx - w * 0.5f; pl[k][1] = cy - h * 0.5f;
                pl[k][2] = cx + w * 0.5f; pl[k][3] = cy + h * 0.5f;
                pa[k] = (pl[k][2] - pl[k][0]) * (pl[k][3] - pl[k][1]);   // ref computes area from ltrb
            }
            #pragma unroll
            for (int m = 0; m < NB; ++m) {
                float cx = (gv[4*m + 0] + fj) * INV_GRID;
                float cy = (gv[4*m + 1] + fi) * INV_GRID;
                float w = gv[4*m + 2], h = gv[4*m + 3];
                gl[m][0] = cx - w * 0.5f; gl[m][1] = cy - h * 0.5f;
                gl[m][2] = cx + w * 0.5f; gl[m][3] = cy + h * 0.5f;
                ga[m] = (gl[m][2] - gl[m][0]) * (gl[m][3] - gl[m][1]);
            }

            // ---- iou(pred k, gt m) and argmax over k (first-max on ties) ----
            int ind[NB];
            #pragma unroll
            for (int m = 0; m < NB; ++m) {
                float iou_km[NB];
                #pragma unroll
                for (int k = 0; k < NB; ++k) {
                    float ltx = fmaxf(pl[k][0], gl[m][0]);
                    float lty = fmaxf(pl[k][1], gl[m][1]);
                    float rbx = fminf(pl[k][2], gl[m][2]);
                    float rby = fminf(pl[k][3], gl[m][3]);
                    float w = fmaxf(rbx - ltx, 0.0f);
                    float h = fmaxf(rby - lty, 0.0f);
                    float inter = w * h;
                    iou_km[k] = inter / (pa[k] + ga[m] - inter + 1e-7f);
                }
                ind[m] = (iou_km[1] > iou_km[0]) ? 1 : 0;   // jnp.argmax: first max wins
            }

            // gathered[m] = poff[ind[m]]  (size-2 select, keep in registers)
            float gth0[4], gth1[4];
            #pragma unroll
            for (int c = 0; c < 4; ++c) {
                gth0[c] = ind[0] ? po[1][c] : po[0][c];
                gth1[c] = ind[1] ? po[1][c] : po[0][c];
            }

            // same_g: exact elementwise equality of the two gt boxes
            bool same_g = (gv[0] == gv[4]) && (gv[1] == gv[5]) &&
                          (gv[2] == gv[6]) && (gv[3] == gv[7]);
            bool same_ind = (ind[0] == ind[1]);

            float lossA = box_loss(gth0, &gv[0]);
            float lossB = box_loss(po[0], &gv[0]) + box_loss(po[1], &gv[4]);
            float lossC = box_loss(gth0, &gv[0]) + box_loss(gth1, &gv[4]);
            float box_cell = same_g ? lossA : (same_ind ? lossB : lossC);

            float pc0 = pv[IS], pc1 = pv[IS + 1];
            float confA = bce(ind[1] ? pc1 : pc0, 1.0f);
            float confBC = bce(pc0, 1.0f) + bce(pc1, 1.0f);
            float conf_cell = same_g ? confA : confBC;

            acc = 5.0f * box_cell + conf_cell + cls;
        }
        // conf_g < 0: contributes nothing (matches reference masks)
    }

    // ---- block reduction: wave shuffle -> LDS -> one atomic per block ----
    #pragma unroll
    for (int off = 32; off > 0; off >>= 1) acc += __shfl_down(acc, off, 64);

    __shared__ float ws_red[4];
    const int lane = threadIdx.x & 63;
    const int wid = threadIdx.x >> 6;
    if (lane == 0) ws_red[wid] = acc;
    __syncthreads();
    if (threadIdx.x == 0) {
        float s = ws_red[0] + ws_red[1] + ws_red[2] + ws_red[3];
        atomicAdd(out, s * INV_BATCH);
    }
}

extern "C" void kernel_launch(void* const* d_in, const int* in_sizes, int n_in,
                              void* d_out, int out_size, void* d_ws, size_t ws_size,
                              hipStream_t stream) {
    const float* p = (const float*)d_in[0];
    const float* g = (const float*)d_in[1];
    float* out = (float*)d_out;

    hipMemsetAsync(out, 0, sizeof(float), stream);   // d_out is poisoned 0xAA each call

    const int block = 256;
    const int grid = (NCELL + block - 1) / block;    // 1568 blocks
    yolo_loss_kernel<<<grid, block, 0, stream>>>(p, g, out);
}